// Round 11
// baseline (498.458 us; speedup 1.0000x reference)
//
#include <hip/hip_runtime.h>
#include <hip/hip_cooperative_groups.h>
#include <math.h>

namespace cg = cooperative_groups;

#define A_W 0.955f
#define B_W 1.3693f
#define INF_W 1e6f
#define HDIM 512
#define WDIM 512
#define NPIX (HDIM*WDIM)
#define NSAMP 16
#define NTOT_F 4194304.0f
#define TST 16      // strip height
#define NSTRIP 32   // strips per sample

// ws layout (bytes):
//  [0,384):     float acc[96]            (fallback)
//  [512,768):   int flags[64]            (fallback)
//  [1024,5120): int blkflags_fb[1024]    (fallback)
//  [4096? no — mega uses 6144,8192): see OFF_BF2
//  [8192,20480):   float stripacc[6][512]
//  [1MB,2MB):      float Llast[16][32][512]
//  [2MB,3MB):      float bounds[16][32][512]
//  [3MB,19MB):     float dB (fallback only)
#define OFF_BF2    6144           // int blkflags2[512] for mega (ends at 8192)
#define OFF_SACC   8192
#define OFF_LLAST  (1u<<20)
#define OFF_BOUNDS (2u<<20)
#define OFF_DB     (3u<<20)

// DPP move with INF fill (floats).
//   WAVE_SHR1 (0x138): lane i <- lane i-1 (== __shfl_up 1)
//   WAVE_SHL1 (0x130): lane i <- lane i+1 (== __shfl_down 1)
template<int CTRL, int RMASK>
__device__ __forceinline__ float dpp_mov_inf(float x) {
    return __int_as_float(__builtin_amdgcn_update_dpp(
        __float_as_int(INF_W), __float_as_int(x), CTRL, RMASK, 0xF, false));
}
template<int CTRL>
__device__ __forceinline__ int dpp_mov0_i(int x) {
    return __builtin_amdgcn_update_dpp(0, x, CTRL, 0xF, 0xF, true);
}

__device__ __forceinline__ float wave_prefix_min_incl(float t) {
    t = fminf(t, dpp_mov_inf<0x111,0xF>(t));
    t = fminf(t, dpp_mov_inf<0x112,0xF>(t));
    t = fminf(t, dpp_mov_inf<0x114,0xF>(t));
    t = fminf(t, dpp_mov_inf<0x118,0xF>(t));
    t = fminf(t, dpp_mov_inf<0x142,0xA>(t));
    t = fminf(t, dpp_mov_inf<0x143,0xC>(t));
    return t;
}

__device__ __forceinline__ void cummin_row(const float* jc, float* v) {
    float g[8];
#pragma unroll
    for (int i = 0; i < 8; ++i) g[i] = v[i] - jc[i];
    float c1[8];
    c1[0] = g[0];
#pragma unroll
    for (int i = 1; i < 8; ++i) c1[i] = fminf(g[i], g[i-1]);
    float c2[8];
    c2[0] = c1[0]; c2[1] = c1[1];
#pragma unroll
    for (int i = 2; i < 8; ++i) c2[i] = fminf(c1[i], c1[i-2]);
    float cj[8];
    cj[0] = c2[0]; cj[1] = c2[1]; cj[2] = c2[2]; cj[3] = c2[3];
#pragma unroll
    for (int i = 4; i < 8; ++i) cj[i] = fminf(c2[i], c2[i-4]);
    float t  = wave_prefix_min_incl(cj[7]);
    float ex = dpp_mov_inf<0x138,0xF>(t);
#pragma unroll
    for (int i = 0; i < 8; ++i) v[i] = jc[i] + fminf(cj[i], ex);
}

__device__ __forceinline__ void row_step(const float* jc, float* prev, const float* drow) {
    float lIn = dpp_mov_inf<0x138,0xF>(prev[7]);
    float rIn = dpp_mov_inf<0x130,0xF>(prev[0]);
    float m[8];
#pragma unroll
    for (int i = 0; i < 8; ++i) {
        float up = prev[i] + A_W;
        float ul = ((i == 0) ? lIn : prev[i-1]) + B_W;
        float ur = ((i == 7) ? rIn : prev[i+1]) + B_W;
        m[i] = fminf(fminf(drow[i], up), fminf(ul, ur));
    }
    cummin_row(jc, m);
#pragma unroll
    for (int i = 0; i < 8; ++i) prev[i] = m[i];
}

// 4 fused T3 steps (exact, INF outside grid).
__device__ __forceinline__ void t3x4(float* b) {
    float e[16];
#pragma unroll
    for (int k = 0; k < 4; ++k) e[k]    = dpp_mov_inf<0x138,0xF>(b[4+k]);
#pragma unroll
    for (int k = 0; k < 8; ++k) e[4+k]  = b[k];
#pragma unroll
    for (int k = 0; k < 4; ++k) e[12+k] = dpp_mov_inf<0x130,0xF>(b[k]);
    const float w0 = 4.f*A_W, w1 = 3.f*A_W + B_W, w2 = 2.f*A_W + 2.f*B_W;
    const float w3 = A_W + 3.f*B_W, w4 = 4.f*B_W;
#pragma unroll
    for (int i = 0; i < 8; ++i) {
        float m = e[i+4] + w0;
        m = fminf(m, fminf(e[i+3], e[i+5]) + w1);
        m = fminf(m, fminf(e[i+2], e[i+6]) + w2);
        m = fminf(m, fminf(e[i+1], e[i+7]) + w3);
        m = fminf(m, fminf(e[i+0], e[i+8]) + w4);
        b[i] = m;
    }
}

struct RowBits { int efg; int ebg; int rawbg; };

__device__ __forceinline__ RowBits make_rowbits(uint4 a, uint4 b) {
    int fg = ((a.x!=0u)?1:0) | ((a.y!=0u)?2:0) | ((a.z!=0u)?4:0) | ((a.w!=0u)?8:0)
           | ((b.x!=0u)?16:0) | ((b.y!=0u)?32:0) | ((b.z!=0u)?64:0) | ((b.w!=0u)?128:0);
    int bg = (~fg) & 0xFF;
    int lf = dpp_mov0_i<0x138>(fg), rf = dpp_mov0_i<0x130>(fg);
    int lb = dpp_mov0_i<0x138>(bg), rb = dpp_mov0_i<0x130>(bg);
    RowBits r;
    r.efg = (fg | (fg<<1) | (fg>>1) | ((lf>>7)&1) | ((rf&1)<<7)) & 0xFF;
    r.ebg = (bg | (bg<<1) | (bg>>1) | ((lb>>7)&1) | ((rb&1)<<7)) & 0xFF;
    r.rawbg = bg;
    return r;
}

__device__ __forceinline__ RowBits loadrow_bits(const int* tgb, int rr, int c0) {
    if (rr < 0 || rr >= HDIM) { RowBits z; z.efg = 0; z.ebg = 0; z.rawbg = 0; return z; }
    const uint4* p = (const uint4*)(tgb + (size_t)rr * WDIM + c0);
    return make_rowbits(p[0], p[1]);
}

// Exact sequential boundary propagation across 32 strips (one wave).
__device__ __forceinline__ void bounds_scan(const float* __restrict__ Lb,
                                            float* __restrict__ Bb,
                                            const float* jc, int c0) {
    float b[8];
    float4 l0 = *(const float4*)(Lb + c0);
    float4 l1 = *(const float4*)(Lb + c0 + 4);
    b[0]=l0.x; b[1]=l0.y; b[2]=l0.z; b[3]=l0.w;
    b[4]=l1.x; b[5]=l1.y; b[6]=l1.z; b[7]=l1.w;
    *(float4*)(Bb + c0)     = l0;
    *(float4*)(Bb + c0 + 4) = l1;
    for (int sg = 1; sg < NSTRIP; ++sg) {
        const float* Lr = Lb + (size_t)sg * WDIM + c0;
        float4 m0 = *(const float4*)Lr;
        float4 m1 = *(const float4*)(Lr + 4);
        t3x4(b); t3x4(b); t3x4(b); t3x4(b);      // T3^16 exact (TST==16)
        cummin_row(jc, b);
        b[0]=fminf(b[0],m0.x); b[1]=fminf(b[1],m0.y); b[2]=fminf(b[2],m0.z); b[3]=fminf(b[3],m0.w);
        b[4]=fminf(b[4],m1.x); b[5]=fminf(b[5],m1.y); b[6]=fminf(b[6],m1.z); b[7]=fminf(b[7],m1.w);
        float* Br = Bb + (size_t)sg * WDIM + c0;
        *(float4*)Br       = make_float4(b[0], b[1], b[2], b[3]);
        *(float4*)(Br + 4) = make_float4(b[4], b[5], b[6], b[7]);
    }
}

// ============================ MEGA (cooperative) ============================
// 512 blocks x 64 threads; block b: sample s=b>>5, physical strip sig=b&31.
// Phases (grid.sync between): A flags, B strip1a, C bounds1, D strip3a(->LDS)
// + flipped local scan, E bounds2, F pass-2 rows from LDS + fused loss, G final.
__global__ __launch_bounds__(64) void mega_kernel(
    const float* __restrict__ pred, const int* __restrict__ tg,
    const float* __restrict__ lv, float* __restrict__ out,
    int* __restrict__ bf2, float* __restrict__ sacc,
    float* __restrict__ Llast, float* __restrict__ bounds)
{
    cg::grid_group grid = cg::this_grid();
    const int b = blockIdx.x;
    const int lane = threadIdx.x;
    const int s = b >> 5, sig = b & 31;
    const int c0 = lane * 8;
    const int R0 = sig * TST;
    float jc[8];
#pragma unroll
    for (int i = 0; i < 8; ++i) jc[i] = A_W * (float)(c0 + i);

    __shared__ float lds[TST][WDIM];   // this block's pass-1 strip rows (32 KB)

    // ---- Phase A: per-block fg/bg flags over a 32 KB tg chunk ----
    {
        const int4* p = (const int4*)tg + (size_t)b * 2048 + lane;
        int fgany = 0, bgany = 0;
#pragma unroll 4
        for (int i = 0; i < 32; ++i) {
            int4 v = p[i * 64];
            fgany |= (v.x | v.y | v.z | v.w);
            bgany |= (v.x == 0) | (v.y == 0) | (v.z == 0) | (v.w == 0);
        }
        int wf = __any(fgany != 0) ? 1 : 0;
        int wb = __any(bgany != 0) ? 2 : 0;
        if (lane == 0) bf2[b] = wf | wb;
    }
    grid.sync();

    // derive per-sample flag (chunks 32s..32s+31 belong to sample s)
    int fv = bf2[s * 32 + (lane & 31)];
#pragma unroll
    for (int off = 16; off > 0; off >>= 1) fv |= __shfl_xor(fv, off);
    const bool useb = (fv & 3) == 3;   // has_fg && has_bg  <=>  boundary nonempty
    const int* tgb = tg + (size_t)s * NPIX;

    // ---- Phase B: pass-1 local strip scan (INF incoming) -> Llast ----
    {
        RowBits rA = loadrow_bits(tgb, R0 - 1, c0);
        RowBits rB = loadrow_bits(tgb, R0, c0);
        float prev[8];
#pragma unroll
        for (int i = 0; i < 8; ++i) prev[i] = INF_W;
#pragma unroll 4
        for (int t = 0; t < TST; ++t) {
            RowBits rC = loadrow_bits(tgb, R0 + t + 1, c0);
            int smask = useb ? ((rA.efg | rB.efg | rC.efg) & (rA.ebg | rB.ebg | rC.ebg))
                             : rB.rawbg;
            float dr[8];
#pragma unroll
            for (int i = 0; i < 8; ++i) dr[i] = ((smask >> i) & 1) ? 0.f : INF_W;
            row_step(jc, prev, dr);
            rA = rB; rB = rC;
        }
        float* Lr = Llast + ((size_t)s * NSTRIP + sig) * WDIM + c0;
        *(float4*)Lr       = make_float4(prev[0], prev[1], prev[2], prev[3]);
        *(float4*)(Lr + 4) = make_float4(prev[4], prev[5], prev[6], prev[7]);
    }
    grid.sync();

    // ---- Phase C: bounds1 (blocks 0..15, pass-1 strip order) ----
    if (b < NSAMP)
        bounds_scan(Llast + (size_t)b * NSTRIP * WDIM, bounds + (size_t)b * NSTRIP * WDIM, jc, c0);
    grid.sync();

    // ---- Phase D: exact pass-1 rows -> LDS; then flipped local scan -> Llast ----
    {
        float prev[8];
        if (sig == 0) {
#pragma unroll
            for (int i = 0; i < 8; ++i) prev[i] = INF_W;
        } else {
            const float* Br = bounds + ((size_t)s * NSTRIP + (sig - 1)) * WDIM + c0;
            float4 b0 = *(const float4*)Br;
            float4 b1 = *(const float4*)(Br + 4);
            prev[0]=b0.x; prev[1]=b0.y; prev[2]=b0.z; prev[3]=b0.w;
            prev[4]=b1.x; prev[5]=b1.y; prev[6]=b1.z; prev[7]=b1.w;
        }
        RowBits rA = loadrow_bits(tgb, R0 - 1, c0);
        RowBits rB = loadrow_bits(tgb, R0, c0);
#pragma unroll 4
        for (int t = 0; t < TST; ++t) {
            RowBits rC = loadrow_bits(tgb, R0 + t + 1, c0);
            int smask = useb ? ((rA.efg | rB.efg | rC.efg) & (rA.ebg | rB.ebg | rC.ebg))
                             : rB.rawbg;
            float dr[8];
#pragma unroll
            for (int i = 0; i < 8; ++i) dr[i] = ((smask >> i) & 1) ? 0.f : INF_W;
            row_step(jc, prev, dr);
            *(float4*)&lds[t][c0]     = make_float4(prev[0], prev[1], prev[2], prev[3]);
            *(float4*)&lds[t][c0 + 4] = make_float4(prev[4], prev[5], prev[6], prev[7]);
            rA = rB; rB = rC;
        }
        __syncthreads();
        // flipped (pass-2) local scan over this strip, INF incoming
#pragma unroll
        for (int i = 0; i < 8; ++i) prev[i] = INF_W;
#pragma unroll 4
        for (int t2 = 0; t2 < TST; ++t2) {
            float4 a = *(const float4*)&lds[TST - 1 - t2][504 - c0];
            float4 q = *(const float4*)&lds[TST - 1 - t2][508 - c0];
            float dr[8];
            dr[7]=a.x; dr[6]=a.y; dr[5]=a.z; dr[4]=a.w;
            dr[3]=q.x; dr[2]=q.y; dr[1]=q.z; dr[0]=q.w;
            row_step(jc, prev, dr);
        }
        const int sig2 = 31 - sig;    // pass-2 strip index of this physical strip
        float* Lr = Llast + ((size_t)s * NSTRIP + sig2) * WDIM + c0;
        *(float4*)Lr       = make_float4(prev[0], prev[1], prev[2], prev[3]);
        *(float4*)(Lr + 4) = make_float4(prev[4], prev[5], prev[6], prev[7]);
    }
    grid.sync();

    // ---- Phase E: bounds2 ----
    if (b < NSAMP)
        bounds_scan(Llast + (size_t)b * NSTRIP * WDIM, bounds + (size_t)b * NSTRIP * WDIM, jc, c0);
    grid.sync();

    // ---- Phase F: pass-2 exact rows from LDS + fused loss ----
    {
        const int sig2 = 31 - sig;
        float prev[8];
        if (sig2 == 0) {
#pragma unroll
            for (int i = 0; i < 8; ++i) prev[i] = INF_W;
        } else {
            const float* Br = bounds + ((size_t)s * NSTRIP + (sig2 - 1)) * WDIM + c0;
            float4 b0 = *(const float4*)Br;
            float4 b1 = *(const float4*)(Br + 4);
            prev[0]=b0.x; prev[1]=b0.y; prev[2]=b0.z; prev[3]=b0.w;
            prev[4]=b1.x; prev[5]=b1.y; prev[6]=b1.z; prev[7]=b1.w;
        }
        float mx = 0.f, facc = 0.f, s1 = 0.f, s2 = 0.f, iacc = 0.f, pacc = 0.f;
#pragma unroll 2
        for (int t2 = 0; t2 < TST; ++t2) {
            const int tl = TST - 1 - t2;                  // local row (phys row R0+tl)
            const size_t rbase = (size_t)s * NPIX + (size_t)(R0 + tl) * WDIM + (504 - c0);
            float4 a = *(const float4*)&lds[tl][504 - c0];
            float4 q = *(const float4*)&lds[tl][508 - c0];
            float dr[8];
            dr[7]=a.x; dr[6]=a.y; dr[5]=a.z; dr[4]=a.w;
            dr[3]=q.x; dr[2]=q.y; dr[1]=q.z; dr[0]=q.w;
            float4 xa = *(const float4*)(pred + rbase);
            float4 xb = *(const float4*)(pred + rbase + 4);
            float px[8];
            px[7]=xa.x; px[6]=xa.y; px[5]=xa.z; px[4]=xa.w;
            px[3]=xb.x; px[2]=xb.y; px[1]=xb.z; px[0]=xb.w;
            int4 ta = *(const int4*)(tg + rbase);
            int4 tb = *(const int4*)(tg + rbase + 4);
            int ti[8];
            ti[7]=ta.x; ti[6]=ta.y; ti[5]=ta.z; ti[4]=ta.w;
            ti[3]=tb.x; ti[2]=tb.y; ti[1]=tb.z; ti[0]=tb.w;

            row_step(jc, prev, dr);
#pragma unroll
            for (int i = 0; i < 8; ++i) {
                float x = px[i];
                float dd = prev[i];
                float e = __expf(-fabsf(x));
                float inv = 1.f / (1.f + e);
                float pr_ = (x >= 0.f) ? inv : (1.f - inv);
                float L = __logf(1.f + e);
                bool t1 = ti[i] != 0;
                float fo = t1 ? 0.25f * (1.f - pr_) * (1.f - pr_) * (fmaxf(-x, 0.f) + L)
                              : 0.75f * pr_ * pr_ * (fmaxf(x, 0.f) + L);
                facc += fo;
                float base = t1 ? (1.f - pr_) : pr_;
                s1 += base;
                s2 += base * dd;
                float tf = t1 ? 1.f : 0.f;
                iacc += tf * pr_;
                pacc += pr_ + tf;
                mx = fmaxf(mx, dd);
            }
        }
#pragma unroll
        for (int off = 32; off > 0; off >>= 1) {
            facc += __shfl_xor(facc, off);
            s1   += __shfl_xor(s1, off);
            s2   += __shfl_xor(s2, off);
            iacc += __shfl_xor(iacc, off);
            pacc += __shfl_xor(pacc, off);
            mx    = fmaxf(mx, __shfl_xor(mx, off));
        }
        if (lane == 0) {
            const int idx = s * NSTRIP + sig2;
            sacc[0 * 512 + idx] = s1;
            sacc[1 * 512 + idx] = s2;
            sacc[2 * 512 + idx] = iacc;
            sacc[3 * 512 + idx] = pacc;
            sacc[4 * 512 + idx] = mx;
            sacc[5 * 512 + idx] = facc;
        }
    }
    grid.sync();

    // ---- Phase G: final reduction + outputs (block 0) ----
    if (b == 0) {
        const int j = lane & 31;
        float fsum = 0.f, bsum = 0.f, dsum = 0.f, isum = 0.f;
        for (int k = 0; k < 8; ++k) {
            int ss = 2 * k + (lane >> 5);
            int idx = ss * NSTRIP + j;
            float t1 = sacc[0 * 512 + idx];
            float t2 = sacc[1 * 512 + idx];
            float ia = sacc[2 * 512 + idx];
            float pa = sacc[3 * 512 + idx];
            float mx = sacc[4 * 512 + idx];
            float fa = sacc[5 * 512 + idx];
            int   vv = bf2[ss * 32 + j];
#pragma unroll
            for (int off = 16; off > 0; off >>= 1) {
                t1 += __shfl_xor(t1, off);
                t2 += __shfl_xor(t2, off);
                ia += __shfl_xor(ia, off);
                pa += __shfl_xor(pa, off);
                fa += __shfl_xor(fa, off);
                mx  = fmaxf(mx, __shfl_xor(mx, off));
                vv |= __shfl_xor(vv, off);
            }
            bool hfg = (vv & 1) != 0;
            if (j == 0) {
                fsum += fa;
                float distsum = hfg ? ((mx > 0.f) ? t2 / fmaxf(mx, 1e-12f) : 0.f) : t1;
                bsum += t1 + distsum;
                dsum += (2.f * ia + 1e-6f) / (pa + 1e-6f);
                isum += (ia + 1e-6f) / (pa - ia + 1e-6f);
            }
        }
        fsum += __shfl_xor(fsum, 32);
        bsum += __shfl_xor(bsum, 32);
        dsum += __shfl_xor(dsum, 32);
        isum += __shfl_xor(isum, 32);
        if (lane == 0) {
            float focal = fsum / NTOT_F;
            float bnd   = bsum / NTOT_F;
            float dice = 1.f - dsum / 16.f;
            float iou  = 1.f - isum / 16.f;
            float l0 = lv[0], l1 = lv[1], l2 = lv[2], l3 = lv[3];
            float total = expf(-l0) * focal + l0 + expf(-l1) * dice + l1
                        + expf(-l2) * bnd  + l2 + expf(-l3) * iou  + l3;
            out[0] = total; out[1] = focal; out[2] = dice; out[3] = bnd; out[4] = iou;
        }
    }
}

// ============================ FALLBACK (round-10) ============================
__global__ __launch_bounds__(256) void flags1_kernel(const int* __restrict__ tg,
                                                     int* __restrict__ blkflags) {
    const int4* p = (const int4*)tg + (size_t)blockIdx.x * 4096 + threadIdx.x;
    int fgany = 0, bgany = 0;
#pragma unroll 4
    for (int i = 0; i < 16; ++i) {
        int4 v = p[i * 256];
        fgany |= (v.x | v.y | v.z | v.w);
        bgany |= (v.x == 0) | (v.y == 0) | (v.z == 0) | (v.w == 0);
    }
    int wf = __any(fgany != 0) ? 1 : 0;
    int wb = __any(bgany != 0) ? 2 : 0;
    if ((threadIdx.x & 63) == 0) blkflags[blockIdx.x * 4 + (threadIdx.x >> 6)] = wf | wb;
}

__global__ __launch_bounds__(64) void flags2_kernel(const int* __restrict__ blkflags,
                                                    int* __restrict__ flags) {
    const int s = blockIdx.x;
    const int lane = threadIdx.x;
    int v = blkflags[s * 64 + lane];
#pragma unroll
    for (int off = 32; off > 0; off >>= 1) v |= __shfl_xor(v, off);
    if (lane == 0) {
        int hfg = v & 1, hbg = (v >> 1) & 1;
        flags[s] = hfg & hbg;
        flags[16 + s] = hfg;
    }
}

__global__ __launch_bounds__(64) void strip1a_kernel(const int* __restrict__ tg,
                                                     const int* __restrict__ flags,
                                                     float* __restrict__ Llast) {
    const int s = blockIdx.x >> 5, sig = blockIdx.x & 31;
    const int lane = threadIdx.x;
    const int c0 = lane * 8;
    const int* tgb = tg + (size_t)s * NPIX;
    const bool useb = flags[s] != 0;
    const int R0 = sig * TST;
    float jc[8];
#pragma unroll
    for (int i = 0; i < 8; ++i) jc[i] = A_W * (float)(c0 + i);
    RowBits rA = loadrow_bits(tgb, R0 - 1, c0);
    RowBits rB = loadrow_bits(tgb, R0, c0);
    float prev[8];
#pragma unroll
    for (int i = 0; i < 8; ++i) prev[i] = INF_W;
#pragma unroll
    for (int t = 0; t < TST; ++t) {
        RowBits rC = loadrow_bits(tgb, R0 + t + 1, c0);
        int smask = useb ? ((rA.efg | rB.efg | rC.efg) & (rA.ebg | rB.ebg | rC.ebg))
                         : rB.rawbg;
        float dr[8];
#pragma unroll
        for (int i = 0; i < 8; ++i) dr[i] = ((smask >> i) & 1) ? 0.f : INF_W;
        row_step(jc, prev, dr);
        rA = rB; rB = rC;
    }
    float* Lr = Llast + ((size_t)s * NSTRIP + sig) * WDIM + c0;
    *(float4*)Lr       = make_float4(prev[0], prev[1], prev[2], prev[3]);
    *(float4*)(Lr + 4) = make_float4(prev[4], prev[5], prev[6], prev[7]);
}

__global__ __launch_bounds__(64) void bounds_kernel(const float* __restrict__ Llast,
                                                    float* __restrict__ bounds) {
    const int s = blockIdx.x;
    const int lane = threadIdx.x;
    const int c0 = lane * 8;
    float jc[8];
#pragma unroll
    for (int i = 0; i < 8; ++i) jc[i] = A_W * (float)(c0 + i);
    bounds_scan(Llast + (size_t)s * NSTRIP * WDIM, bounds + (size_t)s * NSTRIP * WDIM, jc, c0);
}

__global__ __launch_bounds__(64) void strip3a_kernel(const int* __restrict__ tg,
                                                     const int* __restrict__ flags,
                                                     const float* __restrict__ bounds,
                                                     float* __restrict__ dB) {
    const int s = blockIdx.x >> 5, sig = blockIdx.x & 31;
    const int lane = threadIdx.x;
    const int c0 = lane * 8;
    const int* tgb = tg + (size_t)s * NPIX;
    const bool useb = flags[s] != 0;
    const int R0 = sig * TST;
    float jc[8];
#pragma unroll
    for (int i = 0; i < 8; ++i) jc[i] = A_W * (float)(c0 + i);
    RowBits rA = loadrow_bits(tgb, R0 - 1, c0);
    RowBits rB = loadrow_bits(tgb, R0, c0);
    float prev[8];
    if (sig == 0) {
#pragma unroll
        for (int i = 0; i < 8; ++i) prev[i] = INF_W;
    } else {
        const float* Br = bounds + ((size_t)s * NSTRIP + (sig - 1)) * WDIM + c0;
        float4 b0 = *(const float4*)Br;
        float4 b1 = *(const float4*)(Br + 4);
        prev[0]=b0.x; prev[1]=b0.y; prev[2]=b0.z; prev[3]=b0.w;
        prev[4]=b1.x; prev[5]=b1.y; prev[6]=b1.z; prev[7]=b1.w;
    }
    float* dst = dB + (size_t)s * NPIX + (size_t)R0 * WDIM;
#pragma unroll
    for (int t = 0; t < TST; ++t) {
        RowBits rC = loadrow_bits(tgb, R0 + t + 1, c0);
        int smask = useb ? ((rA.efg | rB.efg | rC.efg) & (rA.ebg | rB.ebg | rC.ebg))
                         : rB.rawbg;
        float dr[8];
#pragma unroll
        for (int i = 0; i < 8; ++i) dr[i] = ((smask >> i) & 1) ? 0.f : INF_W;
        row_step(jc, prev, dr);
        float* p = dst + (size_t)t * WDIM + c0;
        *(float4*)p       = make_float4(prev[0], prev[1], prev[2], prev[3]);
        *(float4*)(p + 4) = make_float4(prev[4], prev[5], prev[6], prev[7]);
        rA = rB; rB = rC;
    }
}

__global__ __launch_bounds__(64) void strip1b_kernel(const float* __restrict__ dB,
                                                     float* __restrict__ Llast) {
    const int s = blockIdx.x >> 5, sig = blockIdx.x & 31;
    const int lane = threadIdx.x;
    const int c0 = lane * 8;
    const size_t sb = (size_t)s * NPIX;
    float jc[8];
#pragma unroll
    for (int i = 0; i < 8; ++i) jc[i] = A_W * (float)(c0 + i);
    float prev[8];
#pragma unroll
    for (int i = 0; i < 8; ++i) prev[i] = INF_W;
#pragma unroll
    for (int t = 0; t < TST; ++t) {
        int pr = HDIM - 1 - (sig * TST + t);
        const float* p = dB + sb + (size_t)pr * WDIM + (WDIM - 8 - c0);
        float4 a = *(const float4*)p;
        float4 b = *(const float4*)(p + 4);
        float dr[8];
        dr[7]=a.x; dr[6]=a.y; dr[5]=a.z; dr[4]=a.w;
        dr[3]=b.x; dr[2]=b.y; dr[1]=b.z; dr[0]=b.w;
        row_step(jc, prev, dr);
    }
    float* Lr = Llast + ((size_t)s * NSTRIP + sig) * WDIM + c0;
    *(float4*)Lr       = make_float4(prev[0], prev[1], prev[2], prev[3]);
    *(float4*)(Lr + 4) = make_float4(prev[4], prev[5], prev[6], prev[7]);
}

__global__ __launch_bounds__(64) void strip3b_kernel(const float* __restrict__ dB,
                                                     const float* __restrict__ bounds,
                                                     const float* __restrict__ pred,
                                                     const int* __restrict__ tg,
                                                     float* __restrict__ stripacc) {
    const int s = blockIdx.x >> 5, sig = blockIdx.x & 31;
    const int lane = threadIdx.x;
    const int c0 = lane * 8;
    const size_t sb = (size_t)s * NPIX;
    float jc[8];
#pragma unroll
    for (int i = 0; i < 8; ++i) jc[i] = A_W * (float)(c0 + i);
    float prev[8];
    if (sig == 0) {
#pragma unroll
        for (int i = 0; i < 8; ++i) prev[i] = INF_W;
    } else {
        const float* Br = bounds + ((size_t)s * NSTRIP + (sig - 1)) * WDIM + c0;
        float4 b0 = *(const float4*)Br;
        float4 b1 = *(const float4*)(Br + 4);
        prev[0]=b0.x; prev[1]=b0.y; prev[2]=b0.z; prev[3]=b0.w;
        prev[4]=b1.x; prev[5]=b1.y; prev[6]=b1.z; prev[7]=b1.w;
    }
    float mx = 0.f, facc = 0.f, s1 = 0.f, s2 = 0.f, iacc = 0.f, pacc = 0.f;
#pragma unroll 2
    for (int t = 0; t < TST; ++t) {
        int pr = HDIM - 1 - (sig * TST + t);
        const size_t rbase = sb + (size_t)pr * WDIM + (WDIM - 8 - c0);
        float4 a = *(const float4*)(dB + rbase);
        float4 b = *(const float4*)(dB + rbase + 4);
        float dr[8];
        dr[7]=a.x; dr[6]=a.y; dr[5]=a.z; dr[4]=a.w;
        dr[3]=b.x; dr[2]=b.y; dr[1]=b.z; dr[0]=b.w;
        float4 xa = *(const float4*)(pred + rbase);
        float4 xb = *(const float4*)(pred + rbase + 4);
        float px[8];
        px[7]=xa.x; px[6]=xa.y; px[5]=xa.z; px[4]=xa.w;
        px[3]=xb.x; px[2]=xb.y; px[1]=xb.z; px[0]=xb.w;
        int4 ta = *(const int4*)(tg + rbase);
        int4 tb = *(const int4*)(tg + rbase + 4);
        int ti[8];
        ti[7]=ta.x; ti[6]=ta.y; ti[5]=ta.z; ti[4]=ta.w;
        ti[3]=tb.x; ti[2]=tb.y; ti[1]=tb.z; ti[0]=tb.w;
        row_step(jc, prev, dr);
#pragma unroll
        for (int i = 0; i < 8; ++i) {
            float x = px[i];
            float dd = prev[i];
            float e = __expf(-fabsf(x));
            float inv = 1.f / (1.f + e);
            float pr_ = (x >= 0.f) ? inv : (1.f - inv);
            float L = __logf(1.f + e);
            bool t1 = ti[i] != 0;
            float fo = t1 ? 0.25f * (1.f - pr_) * (1.f - pr_) * (fmaxf(-x, 0.f) + L)
                          : 0.75f * pr_ * pr_ * (fmaxf(x, 0.f) + L);
            facc += fo;
            float base = t1 ? (1.f - pr_) : pr_;
            s1 += base;
            s2 += base * dd;
            float tf = t1 ? 1.f : 0.f;
            iacc += tf * pr_;
            pacc += pr_ + tf;
            mx = fmaxf(mx, dd);
        }
    }
#pragma unroll
    for (int off = 32; off > 0; off >>= 1) {
        facc += __shfl_xor(facc, off);
        s1   += __shfl_xor(s1, off);
        s2   += __shfl_xor(s2, off);
        iacc += __shfl_xor(iacc, off);
        pacc += __shfl_xor(pacc, off);
        mx    = fmaxf(mx, __shfl_xor(mx, off));
    }
    if (lane == 0) {
        const int idx = s * NSTRIP + sig;
        stripacc[0 * 512 + idx] = s1;
        stripacc[1 * 512 + idx] = s2;
        stripacc[2 * 512 + idx] = iacc;
        stripacc[3 * 512 + idx] = pacc;
        stripacc[4 * 512 + idx] = mx;
        stripacc[5 * 512 + idx] = facc;
    }
}

__global__ __launch_bounds__(64) void sampred_kernel(const float* __restrict__ stripacc,
                                                     float* __restrict__ acc) {
    const int s = blockIdx.x;
    const int lane = threadIdx.x;
    const bool v = lane < NSTRIP;
    const int idx = s * NSTRIP + (lane & 31);
    float s1   = v ? stripacc[0 * 512 + idx] : 0.f;
    float s2   = v ? stripacc[1 * 512 + idx] : 0.f;
    float iacc = v ? stripacc[2 * 512 + idx] : 0.f;
    float pacc = v ? stripacc[3 * 512 + idx] : 0.f;
    float mx   = v ? stripacc[4 * 512 + idx] : 0.f;
    float facc = v ? stripacc[5 * 512 + idx] : 0.f;
#pragma unroll
    for (int off = 32; off > 0; off >>= 1) {
        s1   += __shfl_xor(s1, off);
        s2   += __shfl_xor(s2, off);
        iacc += __shfl_xor(iacc, off);
        pacc += __shfl_xor(pacc, off);
        facc += __shfl_xor(facc, off);
        mx    = fmaxf(mx, __shfl_xor(mx, off));
    }
    if (lane == 0) {
        acc[s]      = s1;
        acc[16 + s] = s2;
        acc[32 + s] = iacc;
        acc[48 + s] = pacc;
        acc[64 + s] = mx;
        acc[80 + s] = facc;
    }
}

__global__ void final_kernel(const float* __restrict__ acc, const int* __restrict__ flags,
                             const float* __restrict__ lv, float* __restrict__ out) {
    if (threadIdx.x == 0) {
        float fsum = 0.f, bsum = 0.f, dsum = 0.f, isum = 0.f;
        for (int s = 0; s < NSAMP; ++s) {
            fsum += acc[80 + s];
            float S1 = acc[s], S2 = acc[16 + s], mxs = acc[64 + s];
            bool hfg = flags[16 + s] != 0;
            float distsum = hfg ? ((mxs > 0.f) ? S2 / fmaxf(mxs, 1e-12f) : 0.f) : S1;
            bsum += S1 + distsum;
            float inter = acc[32 + s];
            float tot   = acc[48 + s];
            dsum += (2.f * inter + 1e-6f) / (tot + 1e-6f);
            isum += (inter + 1e-6f) / (tot - inter + 1e-6f);
        }
        float focal = fsum / NTOT_F;
        float bnd   = bsum / NTOT_F;
        float dice = 1.f - dsum / 16.f;
        float iou  = 1.f - isum / 16.f;
        float l0 = lv[0], l1 = lv[1], l2 = lv[2], l3 = lv[3];
        float total = expf(-l0) * focal + l0 + expf(-l1) * dice + l1
                    + expf(-l2) * bnd  + l2 + expf(-l3) * iou  + l3;
        out[0] = total; out[1] = focal; out[2] = dice; out[3] = bnd; out[4] = iou;
    }
}

extern "C" void kernel_launch(void* const* d_in, const int* in_sizes, int n_in,
                              void* d_out, int out_size, void* d_ws, size_t ws_size,
                              hipStream_t stream) {
    const float* pred = (const float*)d_in[0];
    const int*   tg   = (const int*)d_in[1];
    const float* lv   = (const float*)d_in[2];
    float* out = (float*)d_out;
    char* ws = (char*)d_ws;
    float* acc      = (float*)ws;
    int*   flags    = (int*)(ws + 512);
    int*   blkflags = (int*)(ws + 1024);
    int*   bf2      = (int*)(ws + OFF_BF2);
    float* sacc     = (float*)(ws + OFF_SACC);
    float* Llast    = (float*)(ws + OFF_LLAST);
    float* bounds   = (float*)(ws + OFF_BOUNDS);
    float* dB       = (float*)(ws + OFF_DB);

    void* args[] = { (void*)&pred, (void*)&tg, (void*)&lv, (void*)&out,
                     (void*)&bf2, (void*)&sacc, (void*)&Llast, (void*)&bounds };
    hipError_t err = hipLaunchCooperativeKernel((void*)mega_kernel,
                                                dim3(NSAMP * NSTRIP), dim3(64),
                                                args, 0, stream);
    if (err != hipSuccess) {
        // fallback: round-10 multi-kernel pipeline
        flags1_kernel<<<256, 256, 0, stream>>>(tg, blkflags);
        flags2_kernel<<<NSAMP, 64, 0, stream>>>(blkflags, flags);
        strip1a_kernel<<<NSAMP * NSTRIP, 64, 0, stream>>>(tg, flags, Llast);
        bounds_kernel<<<NSAMP, 64, 0, stream>>>(Llast, bounds);
        strip3a_kernel<<<NSAMP * NSTRIP, 64, 0, stream>>>(tg, flags, bounds, dB);
        strip1b_kernel<<<NSAMP * NSTRIP, 64, 0, stream>>>(dB, Llast);
        bounds_kernel<<<NSAMP, 64, 0, stream>>>(Llast, bounds);
        strip3b_kernel<<<NSAMP * NSTRIP, 64, 0, stream>>>(dB, bounds, pred, tg, sacc);
        sampred_kernel<<<NSAMP, 64, 0, stream>>>(sacc, acc);
        final_kernel<<<1, 64, 0, stream>>>(acc, flags, lv, out);
    }
}

// Round 12
// 188.089 us; speedup vs baseline: 2.6501x; 2.6501x over previous
//
#include <hip/hip_runtime.h>
#include <math.h>

#define A_W 0.955f
#define B_W 1.3693f
#define INF_W 1e6f
#define HDIM 512
#define WDIM 512
#define NPIX (HDIM*WDIM)
#define NSAMP 16
#define NTOT_F 4194304.0f
#define TST 16      // strip height
#define NSTRIP 32   // strips per sample

// ws layout (bytes):
//  [1024,5120):  int blkflags[1024]  (64 per sample: bit0=has_fg_chunk, bit1=has_bg_chunk)
//  [8192,20480): float sacc[6][512]
//  [1MB,2MB):    float Llast[16][32][512]   (pass-1 local strip results)
//  [2MB,3MB):    float Llast2[16][32][512]  (pass-2 local strip results)
//  [3MB,19MB):   float dB[16][512][512]     (pass-1 rows)
#define OFF_SACC   8192
#define OFF_LLAST  (1u<<20)
#define OFF_LLAST2 (2u<<20)
#define OFF_DB     (3u<<20)

// DPP move with INF fill (floats).
//   WAVE_SHR1 (0x138): lane i <- lane i-1 (== __shfl_up 1)
//   WAVE_SHL1 (0x130): lane i <- lane i+1 (== __shfl_down 1)
template<int CTRL, int RMASK>
__device__ __forceinline__ float dpp_mov_inf(float x) {
    return __int_as_float(__builtin_amdgcn_update_dpp(
        __float_as_int(INF_W), __float_as_int(x), CTRL, RMASK, 0xF, false));
}
template<int CTRL>
__device__ __forceinline__ int dpp_mov0_i(int x) {
    return __builtin_amdgcn_update_dpp(0, x, CTRL, 0xF, 0xF, true);
}

__device__ __forceinline__ float wave_prefix_min_incl(float t) {
    t = fminf(t, dpp_mov_inf<0x111,0xF>(t));
    t = fminf(t, dpp_mov_inf<0x112,0xF>(t));
    t = fminf(t, dpp_mov_inf<0x114,0xF>(t));
    t = fminf(t, dpp_mov_inf<0x118,0xF>(t));
    t = fminf(t, dpp_mov_inf<0x142,0xA>(t));
    t = fminf(t, dpp_mov_inf<0x143,0xC>(t));
    return t;
}

__device__ __forceinline__ void cummin_row(const float* jc, float* v) {
    float g[8];
#pragma unroll
    for (int i = 0; i < 8; ++i) g[i] = v[i] - jc[i];
    float c1[8];
    c1[0] = g[0];
#pragma unroll
    for (int i = 1; i < 8; ++i) c1[i] = fminf(g[i], g[i-1]);
    float c2[8];
    c2[0] = c1[0]; c2[1] = c1[1];
#pragma unroll
    for (int i = 2; i < 8; ++i) c2[i] = fminf(c1[i], c1[i-2]);
    float cj[8];
    cj[0] = c2[0]; cj[1] = c2[1]; cj[2] = c2[2]; cj[3] = c2[3];
#pragma unroll
    for (int i = 4; i < 8; ++i) cj[i] = fminf(c2[i], c2[i-4]);
    float t  = wave_prefix_min_incl(cj[7]);
    float ex = dpp_mov_inf<0x138,0xF>(t);
#pragma unroll
    for (int i = 0; i < 8; ++i) v[i] = jc[i] + fminf(cj[i], ex);
}

__device__ __forceinline__ void row_step(const float* jc, float* prev, const float* drow) {
    float lIn = dpp_mov_inf<0x138,0xF>(prev[7]);
    float rIn = dpp_mov_inf<0x130,0xF>(prev[0]);
    float m[8];
#pragma unroll
    for (int i = 0; i < 8; ++i) {
        float up = prev[i] + A_W;
        float ul = ((i == 0) ? lIn : prev[i-1]) + B_W;
        float ur = ((i == 7) ? rIn : prev[i+1]) + B_W;
        m[i] = fminf(fminf(drow[i], up), fminf(ul, ur));
    }
    cummin_row(jc, m);
#pragma unroll
    for (int i = 0; i < 8; ++i) prev[i] = m[i];
}

// 4 fused T3 steps (exact, INF outside grid).
__device__ __forceinline__ void t3x4(float* b) {
    float e[16];
#pragma unroll
    for (int k = 0; k < 4; ++k) e[k]    = dpp_mov_inf<0x138,0xF>(b[4+k]);
#pragma unroll
    for (int k = 0; k < 8; ++k) e[4+k]  = b[k];
#pragma unroll
    for (int k = 0; k < 4; ++k) e[12+k] = dpp_mov_inf<0x130,0xF>(b[k]);
    const float w0 = 4.f*A_W, w1 = 3.f*A_W + B_W, w2 = 2.f*A_W + 2.f*B_W;
    const float w3 = A_W + 3.f*B_W, w4 = 4.f*B_W;
#pragma unroll
    for (int i = 0; i < 8; ++i) {
        float m = e[i+4] + w0;
        m = fminf(m, fminf(e[i+3], e[i+5]) + w1);
        m = fminf(m, fminf(e[i+2], e[i+6]) + w2);
        m = fminf(m, fminf(e[i+1], e[i+7]) + w3);
        m = fminf(m, fminf(e[i+0], e[i+8]) + w4);
        b[i] = m;
    }
}

struct RowBits { int efg; int ebg; int rawbg; };

__device__ __forceinline__ RowBits make_rowbits(uint4 a, uint4 b) {
    int fg = ((a.x!=0u)?1:0) | ((a.y!=0u)?2:0) | ((a.z!=0u)?4:0) | ((a.w!=0u)?8:0)
           | ((b.x!=0u)?16:0) | ((b.y!=0u)?32:0) | ((b.z!=0u)?64:0) | ((b.w!=0u)?128:0);
    int bg = (~fg) & 0xFF;
    int lf = dpp_mov0_i<0x138>(fg), rf = dpp_mov0_i<0x130>(fg);
    int lb = dpp_mov0_i<0x138>(bg), rb = dpp_mov0_i<0x130>(bg);
    RowBits r;
    r.efg = (fg | (fg<<1) | (fg>>1) | ((lf>>7)&1) | ((rf&1)<<7)) & 0xFF;
    r.ebg = (bg | (bg<<1) | (bg>>1) | ((lb>>7)&1) | ((rb&1)<<7)) & 0xFF;
    r.rawbg = bg;
    return r;
}

__device__ __forceinline__ RowBits loadrow_bits(const int* tgb, int rr, int c0) {
    if (rr < 0 || rr >= HDIM) { RowBits z; z.efg = 0; z.ebg = 0; z.rawbg = 0; return z; }
    const uint4* p = (const uint4*)(tgb + (size_t)rr * WDIM + c0);
    return make_rowbits(p[0], p[1]);
}

// wave-wide OR-reduce of this sample's 64 chunk flags -> same value in all lanes
__device__ __forceinline__ int sample_flags(const int* __restrict__ blkflags, int s, int lane) {
    int v = blkflags[s * 64 + lane];
#pragma unroll
    for (int off = 32; off > 0; off >>= 1) v |= __shfl_xor(v, off);
    return v;
}

// Inline exact boundary: b_{n-1} from local strip results L[0..n-1] (n>=1).
__device__ __forceinline__ void inline_bounds(const float* __restrict__ Lb, int n,
                                              const float* jc, int c0, float* prev) {
    float b[8];
    const float* Lr = Lb + c0;
    float4 l0 = *(const float4*)Lr;
    float4 l1 = *(const float4*)(Lr + 4);
    b[0]=l0.x; b[1]=l0.y; b[2]=l0.z; b[3]=l0.w;
    b[4]=l1.x; b[5]=l1.y; b[6]=l1.z; b[7]=l1.w;
    for (int sg = 1; sg < n; ++sg) {
        const float* Ls = Lb + (size_t)sg * WDIM + c0;
        float4 m0 = *(const float4*)Ls;
        float4 m1 = *(const float4*)(Ls + 4);
        t3x4(b); t3x4(b); t3x4(b); t3x4(b);      // T3^16 exact (TST==16)
        cummin_row(jc, b);
        b[0]=fminf(b[0],m0.x); b[1]=fminf(b[1],m0.y); b[2]=fminf(b[2],m0.z); b[3]=fminf(b[3],m0.w);
        b[4]=fminf(b[4],m1.x); b[5]=fminf(b[5],m1.y); b[6]=fminf(b[6],m1.z); b[7]=fminf(b[7],m1.w);
    }
#pragma unroll
    for (int i = 0; i < 8; ++i) prev[i] = b[i];
}

// K1: per-chunk fg/bg flags (256 blocks x 256 threads; 64 KB per block).
__global__ __launch_bounds__(256) void flags1_kernel(const int* __restrict__ tg,
                                                     int* __restrict__ blkflags) {
    const int4* p = (const int4*)tg + (size_t)blockIdx.x * 4096 + threadIdx.x;
    int fgany = 0, bgany = 0;
#pragma unroll 4
    for (int i = 0; i < 16; ++i) {
        int4 v = p[i * 256];
        fgany |= (v.x | v.y | v.z | v.w);
        bgany |= (v.x == 0) | (v.y == 0) | (v.z == 0) | (v.w == 0);
    }
    int wf = __any(fgany != 0) ? 1 : 0;
    int wb = __any(bgany != 0) ? 2 : 0;
    if ((threadIdx.x & 63) == 0) blkflags[blockIdx.x * 4 + (threadIdx.x >> 6)] = wf | wb;
}

// K2: pass-1 local strip scan (INF incoming) -> Llast. Inline flag reduce.
__global__ __launch_bounds__(64) void strip1a_kernel(const int* __restrict__ tg,
                                                     const int* __restrict__ blkflags,
                                                     float* __restrict__ Llast) {
    const int s = blockIdx.x >> 5, sig = blockIdx.x & 31;
    const int lane = threadIdx.x;
    const int c0 = lane * 8;
    const int* tgb = tg + (size_t)s * NPIX;
    const int fv = sample_flags(blkflags, s, lane);
    const bool useb = (fv & 3) == 3;     // has_fg && has_bg <=> boundary nonempty
    const int R0 = sig * TST;
    float jc[8];
#pragma unroll
    for (int i = 0; i < 8; ++i) jc[i] = A_W * (float)(c0 + i);
    RowBits rA = loadrow_bits(tgb, R0 - 1, c0);
    RowBits rB = loadrow_bits(tgb, R0, c0);
    float prev[8];
#pragma unroll
    for (int i = 0; i < 8; ++i) prev[i] = INF_W;
#pragma unroll 4
    for (int t = 0; t < TST; ++t) {
        RowBits rC = loadrow_bits(tgb, R0 + t + 1, c0);
        int smask = useb ? ((rA.efg | rB.efg | rC.efg) & (rA.ebg | rB.ebg | rC.ebg))
                         : rB.rawbg;
        float dr[8];
#pragma unroll
        for (int i = 0; i < 8; ++i) dr[i] = ((smask >> i) & 1) ? 0.f : INF_W;
        row_step(jc, prev, dr);
        rA = rB; rB = rC;
    }
    float* Lr = Llast + ((size_t)s * NSTRIP + sig) * WDIM + c0;
    *(float4*)Lr       = make_float4(prev[0], prev[1], prev[2], prev[3]);
    *(float4*)(Lr + 4) = make_float4(prev[4], prev[5], prev[6], prev[7]);
}

// K3: inline bounds1 + exact pass-1 rows -> dB (+LDS) + flipped local scan -> Llast2.
__global__ __launch_bounds__(64) void strip3ab_kernel(const int* __restrict__ tg,
                                                      const int* __restrict__ blkflags,
                                                      const float* __restrict__ Llast,
                                                      float* __restrict__ dB,
                                                      float* __restrict__ Llast2) {
    const int s = blockIdx.x >> 5, sig = blockIdx.x & 31;
    const int lane = threadIdx.x;
    const int c0 = lane * 8;
    const int* tgb = tg + (size_t)s * NPIX;
    const int fv = sample_flags(blkflags, s, lane);
    const bool useb = (fv & 3) == 3;
    const int R0 = sig * TST;
    float jc[8];
#pragma unroll
    for (int i = 0; i < 8; ++i) jc[i] = A_W * (float)(c0 + i);

    __shared__ float lds[TST][WDIM];   // 32 KB; single-wave block

    float prev[8];
    if (sig == 0) {
#pragma unroll
        for (int i = 0; i < 8; ++i) prev[i] = INF_W;
    } else {
        inline_bounds(Llast + (size_t)s * NSTRIP * WDIM, sig, jc, c0, prev);
    }

    RowBits rA = loadrow_bits(tgb, R0 - 1, c0);
    RowBits rB = loadrow_bits(tgb, R0, c0);
    float* dst = dB + (size_t)s * NPIX + (size_t)R0 * WDIM;
#pragma unroll 2
    for (int t = 0; t < TST; ++t) {
        RowBits rC = loadrow_bits(tgb, R0 + t + 1, c0);
        int smask = useb ? ((rA.efg | rB.efg | rC.efg) & (rA.ebg | rB.ebg | rC.ebg))
                         : rB.rawbg;
        float dr[8];
#pragma unroll
        for (int i = 0; i < 8; ++i) dr[i] = ((smask >> i) & 1) ? 0.f : INF_W;
        row_step(jc, prev, dr);
        float* p = dst + (size_t)t * WDIM + c0;
        *(float4*)p       = make_float4(prev[0], prev[1], prev[2], prev[3]);
        *(float4*)(p + 4) = make_float4(prev[4], prev[5], prev[6], prev[7]);
        *(float4*)&lds[t][c0]     = make_float4(prev[0], prev[1], prev[2], prev[3]);
        *(float4*)&lds[t][c0 + 4] = make_float4(prev[4], prev[5], prev[6], prev[7]);
        rA = rB; rB = rC;
    }
    __syncthreads();
    // flipped (pass-2) local scan over this strip, INF incoming
#pragma unroll
    for (int i = 0; i < 8; ++i) prev[i] = INF_W;
#pragma unroll 2
    for (int t2 = 0; t2 < TST; ++t2) {
        float4 a = *(const float4*)&lds[TST - 1 - t2][504 - c0];
        float4 q = *(const float4*)&lds[TST - 1 - t2][508 - c0];
        float dr[8];
        dr[7]=a.x; dr[6]=a.y; dr[5]=a.z; dr[4]=a.w;
        dr[3]=q.x; dr[2]=q.y; dr[1]=q.z; dr[0]=q.w;
        row_step(jc, prev, dr);
    }
    const int sig2 = 31 - sig;
    float* Lr = Llast2 + ((size_t)s * NSTRIP + sig2) * WDIM + c0;
    *(float4*)Lr       = make_float4(prev[0], prev[1], prev[2], prev[3]);
    *(float4*)(Lr + 4) = make_float4(prev[4], prev[5], prev[6], prev[7]);
}

// K4: inline bounds2 + pass-2 exact rows from dB + fused loss -> sacc.
__global__ __launch_bounds__(64) void strip3bloss_kernel(const float* __restrict__ dB,
                                                         const float* __restrict__ Llast2,
                                                         const float* __restrict__ pred,
                                                         const int* __restrict__ tg,
                                                         float* __restrict__ sacc) {
    const int s = blockIdx.x >> 5, sig2 = blockIdx.x & 31;
    const int lane = threadIdx.x;
    const int c0 = lane * 8;
    const size_t sb = (size_t)s * NPIX;
    float jc[8];
#pragma unroll
    for (int i = 0; i < 8; ++i) jc[i] = A_W * (float)(c0 + i);

    float prev[8];
    if (sig2 == 0) {
#pragma unroll
        for (int i = 0; i < 8; ++i) prev[i] = INF_W;
    } else {
        inline_bounds(Llast2 + (size_t)s * NSTRIP * WDIM, sig2, jc, c0, prev);
    }

    float mx = 0.f, facc = 0.f, s1 = 0.f, s2 = 0.f, iacc = 0.f, pacc = 0.f;
#pragma unroll 2
    for (int t = 0; t < TST; ++t) {
        int pr = HDIM - 1 - (sig2 * TST + t);
        const size_t rbase = sb + (size_t)pr * WDIM + (WDIM - 8 - c0);
        float4 a = *(const float4*)(dB + rbase);
        float4 b = *(const float4*)(dB + rbase + 4);
        float dr[8];
        dr[7]=a.x; dr[6]=a.y; dr[5]=a.z; dr[4]=a.w;
        dr[3]=b.x; dr[2]=b.y; dr[1]=b.z; dr[0]=b.w;
        float4 xa = *(const float4*)(pred + rbase);
        float4 xb = *(const float4*)(pred + rbase + 4);
        float px[8];
        px[7]=xa.x; px[6]=xa.y; px[5]=xa.z; px[4]=xa.w;
        px[3]=xb.x; px[2]=xb.y; px[1]=xb.z; px[0]=xb.w;
        int4 ta = *(const int4*)(tg + rbase);
        int4 tb = *(const int4*)(tg + rbase + 4);
        int ti[8];
        ti[7]=ta.x; ti[6]=ta.y; ti[5]=ta.z; ti[4]=ta.w;
        ti[3]=tb.x; ti[2]=tb.y; ti[1]=tb.z; ti[0]=tb.w;
        row_step(jc, prev, dr);
#pragma unroll
        for (int i = 0; i < 8; ++i) {
            float x = px[i];
            float dd = prev[i];
            float e = __expf(-fabsf(x));
            float inv = 1.f / (1.f + e);
            float pr_ = (x >= 0.f) ? inv : (1.f - inv);   // sigmoid(x)
            float L = __logf(1.f + e);                    // softplus(-|x|)
            bool t1 = ti[i] != 0;
            float fo = t1 ? 0.25f * (1.f - pr_) * (1.f - pr_) * (fmaxf(-x, 0.f) + L)
                          : 0.75f * pr_ * pr_ * (fmaxf(x, 0.f) + L);
            facc += fo;
            float base = t1 ? (1.f - pr_) : pr_;
            s1 += base;
            s2 += base * dd;
            float tf = t1 ? 1.f : 0.f;
            iacc += tf * pr_;
            pacc += pr_ + tf;
            mx = fmaxf(mx, dd);
        }
    }
#pragma unroll
    for (int off = 32; off > 0; off >>= 1) {
        facc += __shfl_xor(facc, off);
        s1   += __shfl_xor(s1, off);
        s2   += __shfl_xor(s2, off);
        iacc += __shfl_xor(iacc, off);
        pacc += __shfl_xor(pacc, off);
        mx    = fmaxf(mx, __shfl_xor(mx, off));
    }
    if (lane == 0) {
        const int idx = s * NSTRIP + sig2;
        sacc[0 * 512 + idx] = s1;
        sacc[1 * 512 + idx] = s2;
        sacc[2 * 512 + idx] = iacc;
        sacc[3 * 512 + idx] = pacc;
        sacc[4 * 512 + idx] = mx;
        sacc[5 * 512 + idx] = facc;
    }
}

// K5: merged sampred + final (one 64-lane block; HW-verified pattern from mega Phase G).
__global__ __launch_bounds__(64) void final5_kernel(const float* __restrict__ sacc,
                                                    const int* __restrict__ blkflags,
                                                    const float* __restrict__ lv,
                                                    float* __restrict__ out) {
    const int lane = threadIdx.x;
    const int j = lane & 31;
    float fsum = 0.f, bsum = 0.f, dsum = 0.f, isum = 0.f;
    for (int k = 0; k < 8; ++k) {
        int ss = 2 * k + (lane >> 5);
        int idx = ss * NSTRIP + j;
        float t1 = sacc[0 * 512 + idx];
        float t2 = sacc[1 * 512 + idx];
        float ia = sacc[2 * 512 + idx];
        float pa = sacc[3 * 512 + idx];
        float mx = sacc[4 * 512 + idx];
        float fa = sacc[5 * 512 + idx];
        int   vv = blkflags[ss * 64 + j] | blkflags[ss * 64 + 32 + j];
#pragma unroll
        for (int off = 16; off > 0; off >>= 1) {
            t1 += __shfl_xor(t1, off);
            t2 += __shfl_xor(t2, off);
            ia += __shfl_xor(ia, off);
            pa += __shfl_xor(pa, off);
            fa += __shfl_xor(fa, off);
            mx  = fmaxf(mx, __shfl_xor(mx, off));
            vv |= __shfl_xor(vv, off);
        }
        bool hfg = (vv & 1) != 0;
        if (j == 0) {
            fsum += fa;
            float distsum = hfg ? ((mx > 0.f) ? t2 / fmaxf(mx, 1e-12f) : 0.f) : t1;
            bsum += t1 + distsum;
            dsum += (2.f * ia + 1e-6f) / (pa + 1e-6f);
            isum += (ia + 1e-6f) / (pa - ia + 1e-6f);
        }
    }
    fsum += __shfl_xor(fsum, 32);
    bsum += __shfl_xor(bsum, 32);
    dsum += __shfl_xor(dsum, 32);
    isum += __shfl_xor(isum, 32);
    if (lane == 0) {
        float focal = fsum / NTOT_F;
        float bnd   = bsum / NTOT_F;
        float dice = 1.f - dsum / 16.f;
        float iou  = 1.f - isum / 16.f;
        float l0 = lv[0], l1 = lv[1], l2 = lv[2], l3 = lv[3];
        float total = expf(-l0) * focal + l0 + expf(-l1) * dice + l1
                    + expf(-l2) * bnd  + l2 + expf(-l3) * iou  + l3;
        out[0] = total; out[1] = focal; out[2] = dice; out[3] = bnd; out[4] = iou;
    }
}

extern "C" void kernel_launch(void* const* d_in, const int* in_sizes, int n_in,
                              void* d_out, int out_size, void* d_ws, size_t ws_size,
                              hipStream_t stream) {
    const float* pred = (const float*)d_in[0];
    const int*   tg   = (const int*)d_in[1];
    const float* lv   = (const float*)d_in[2];
    float* out = (float*)d_out;
    char* ws = (char*)d_ws;
    int*   blkflags = (int*)(ws + 1024);
    float* sacc     = (float*)(ws + OFF_SACC);
    float* Llast    = (float*)(ws + OFF_LLAST);
    float* Llast2   = (float*)(ws + OFF_LLAST2);
    float* dB       = (float*)(ws + OFF_DB);

    flags1_kernel<<<256, 256, 0, stream>>>(tg, blkflags);
    strip1a_kernel<<<NSAMP * NSTRIP, 64, 0, stream>>>(tg, blkflags, Llast);
    strip3ab_kernel<<<NSAMP * NSTRIP, 64, 0, stream>>>(tg, blkflags, Llast, dB, Llast2);
    strip3bloss_kernel<<<NSAMP * NSTRIP, 64, 0, stream>>>(dB, Llast2, pred, tg, sacc);
    final5_kernel<<<1, 64, 0, stream>>>(sacc, blkflags, lv, out);
}

// Round 13
// 132.796 us; speedup vs baseline: 3.7536x; 1.4164x over previous
//
#include <hip/hip_runtime.h>
#include <math.h>

#define A_W 0.955f
#define B_W 1.3693f
#define INF_W 1e6f
#define HDIM 512
#define WDIM 512
#define NPIX (HDIM*WDIM)
#define NSAMP 16
#define NTOT_F 4194304.0f
#define TST 16      // strip height
#define NSTRIP 32   // strips per sample
#define STRIP_COST (16.0f * A_W)   // min cost to propagate a boundary through one strip

// ws layout (bytes):
//  [1024,5120):   int blkflags[1024]
//  [8192,20480):  float sacc[6][512]
//  [24576,28672): float mm1[2][512]  (min,max of Llast rows)
//  [28672,32768): float mm2[2][512]  (min,max of Llast2 rows)
//  [1MB,2MB):     float Llast[16][32][512]
//  [2MB,3MB):     float Llast2[16][32][512]
//  [3MB,19MB):    float dB[16][512][512]
#define OFF_SACC   8192
#define OFF_MM1    24576
#define OFF_MM2    28672
#define OFF_LLAST  (1u<<20)
#define OFF_LLAST2 (2u<<20)
#define OFF_DB     (3u<<20)

// DPP move with INF fill (floats).
//   WAVE_SHR1 (0x138): lane i <- lane i-1 (== __shfl_up 1)
//   WAVE_SHL1 (0x130): lane i <- lane i+1 (== __shfl_down 1)
template<int CTRL, int RMASK>
__device__ __forceinline__ float dpp_mov_inf(float x) {
    return __int_as_float(__builtin_amdgcn_update_dpp(
        __float_as_int(INF_W), __float_as_int(x), CTRL, RMASK, 0xF, false));
}
template<int CTRL>
__device__ __forceinline__ int dpp_mov0_i(int x) {
    return __builtin_amdgcn_update_dpp(0, x, CTRL, 0xF, 0xF, true);
}

__device__ __forceinline__ float wave_prefix_min_incl(float t) {
    t = fminf(t, dpp_mov_inf<0x111,0xF>(t));
    t = fminf(t, dpp_mov_inf<0x112,0xF>(t));
    t = fminf(t, dpp_mov_inf<0x114,0xF>(t));
    t = fminf(t, dpp_mov_inf<0x118,0xF>(t));
    t = fminf(t, dpp_mov_inf<0x142,0xA>(t));
    t = fminf(t, dpp_mov_inf<0x143,0xC>(t));
    return t;
}

__device__ __forceinline__ void cummin_row(const float* jc, float* v) {
    float g[8];
#pragma unroll
    for (int i = 0; i < 8; ++i) g[i] = v[i] - jc[i];
    float c1[8];
    c1[0] = g[0];
#pragma unroll
    for (int i = 1; i < 8; ++i) c1[i] = fminf(g[i], g[i-1]);
    float c2[8];
    c2[0] = c1[0]; c2[1] = c1[1];
#pragma unroll
    for (int i = 2; i < 8; ++i) c2[i] = fminf(c1[i], c1[i-2]);
    float cj[8];
    cj[0] = c2[0]; cj[1] = c2[1]; cj[2] = c2[2]; cj[3] = c2[3];
#pragma unroll
    for (int i = 4; i < 8; ++i) cj[i] = fminf(c2[i], c2[i-4]);
    float t  = wave_prefix_min_incl(cj[7]);
    float ex = dpp_mov_inf<0x138,0xF>(t);
#pragma unroll
    for (int i = 0; i < 8; ++i) v[i] = jc[i] + fminf(cj[i], ex);
}

__device__ __forceinline__ void row_step(const float* jc, float* prev, const float* drow) {
    float lIn = dpp_mov_inf<0x138,0xF>(prev[7]);
    float rIn = dpp_mov_inf<0x130,0xF>(prev[0]);
    float m[8];
#pragma unroll
    for (int i = 0; i < 8; ++i) {
        float up = prev[i] + A_W;
        float ul = ((i == 0) ? lIn : prev[i-1]) + B_W;
        float ur = ((i == 7) ? rIn : prev[i+1]) + B_W;
        m[i] = fminf(fminf(drow[i], up), fminf(ul, ur));
    }
    cummin_row(jc, m);
#pragma unroll
    for (int i = 0; i < 8; ++i) prev[i] = m[i];
}

// 4 fused T3 steps (exact, INF outside grid).
__device__ __forceinline__ void t3x4(float* b) {
    float e[16];
#pragma unroll
    for (int k = 0; k < 4; ++k) e[k]    = dpp_mov_inf<0x138,0xF>(b[4+k]);
#pragma unroll
    for (int k = 0; k < 8; ++k) e[4+k]  = b[k];
#pragma unroll
    for (int k = 0; k < 4; ++k) e[12+k] = dpp_mov_inf<0x130,0xF>(b[k]);
    const float w0 = 4.f*A_W, w1 = 3.f*A_W + B_W, w2 = 2.f*A_W + 2.f*B_W;
    const float w3 = A_W + 3.f*B_W, w4 = 4.f*B_W;
#pragma unroll
    for (int i = 0; i < 8; ++i) {
        float m = e[i+4] + w0;
        m = fminf(m, fminf(e[i+3], e[i+5]) + w1);
        m = fminf(m, fminf(e[i+2], e[i+6]) + w2);
        m = fminf(m, fminf(e[i+1], e[i+7]) + w3);
        m = fminf(m, fminf(e[i+0], e[i+8]) + w4);
        b[i] = m;
    }
}

struct RowBits { int efg; int ebg; int rawbg; };

__device__ __forceinline__ RowBits make_rowbits(uint4 a, uint4 b) {
    int fg = ((a.x!=0u)?1:0) | ((a.y!=0u)?2:0) | ((a.z!=0u)?4:0) | ((a.w!=0u)?8:0)
           | ((b.x!=0u)?16:0) | ((b.y!=0u)?32:0) | ((b.z!=0u)?64:0) | ((b.w!=0u)?128:0);
    int bg = (~fg) & 0xFF;
    int lf = dpp_mov0_i<0x138>(fg), rf = dpp_mov0_i<0x130>(fg);
    int lb = dpp_mov0_i<0x138>(bg), rb = dpp_mov0_i<0x130>(bg);
    RowBits r;
    r.efg = (fg | (fg<<1) | (fg>>1) | ((lf>>7)&1) | ((rf&1)<<7)) & 0xFF;
    r.ebg = (bg | (bg<<1) | (bg>>1) | ((lb>>7)&1) | ((rb&1)<<7)) & 0xFF;
    r.rawbg = bg;
    return r;
}

__device__ __forceinline__ RowBits loadrow_bits(const int* tgb, int rr, int c0) {
    if (rr < 0 || rr >= HDIM) { RowBits z; z.efg = 0; z.ebg = 0; z.rawbg = 0; return z; }
    const uint4* p = (const uint4*)(tgb + (size_t)rr * WDIM + c0);
    return make_rowbits(p[0], p[1]);
}

__device__ __forceinline__ int sample_flags(const int* __restrict__ blkflags, int s, int lane) {
    int v = blkflags[s * 64 + lane];
#pragma unroll
    for (int off = 32; off > 0; off >>= 1) v |= __shfl_xor(v, off);
    return v;
}

// store min/max of an L row (prev[8] across wave) into mm arrays
__device__ __forceinline__ void store_minmax(const float* prev, float* __restrict__ mm,
                                             int idx, int lane) {
    float mn = prev[0], mx = prev[0];
#pragma unroll
    for (int i = 1; i < 8; ++i) { mn = fminf(mn, prev[i]); mx = fmaxf(mx, prev[i]); }
#pragma unroll
    for (int off = 32; off > 0; off >>= 1) {
        mn = fminf(mn, __shfl_xor(mn, off));
        mx = fmaxf(mx, __shfl_xor(mx, off));
    }
    if (lane == 0) { mm[idx] = mn; mm[512 + idx] = mx; }
}

// Inline exact boundary with dominance pruning.
// b* = min_{k<=n-1} P^{n-1-k}(L[k]); strip k is skippable (exactly) when
// minL[k] + STRIP_COST*(n-1-k) > maxL[n-1]  (propagation adds >= A per row;
// b*[j] <= L[n-1][j] <= maxL[n-1]).  Ties kept (strict >) => bit-exact.
__device__ __forceinline__ void inline_bounds(const float* __restrict__ Lb, int n,
                                              const float* jc, int c0, float* prev,
                                              const float* __restrict__ mm, int base,
                                              int lane) {
    float ub = mm[512 + base + (n - 1)];                 // maxL[n-1]
    int k = lane;
    bool cond = (k < n) && (mm[base + k] + STRIP_COST * (float)(n - 1 - k) <= ub);
    unsigned long long msk = __ballot((int)cond);
    int k0 = (msk != 0ull) ? (__ffsll((long long)msk) - 1) : (n - 1);

    float b[8];
    const float* Lr = Lb + (size_t)k0 * WDIM + c0;
    float4 l0 = *(const float4*)Lr;
    float4 l1 = *(const float4*)(Lr + 4);
    b[0]=l0.x; b[1]=l0.y; b[2]=l0.z; b[3]=l0.w;
    b[4]=l1.x; b[5]=l1.y; b[6]=l1.z; b[7]=l1.w;
    for (int sg = k0 + 1; sg < n; ++sg) {
        const float* Ls = Lb + (size_t)sg * WDIM + c0;
        float4 m0 = *(const float4*)Ls;
        float4 m1 = *(const float4*)(Ls + 4);
        t3x4(b); t3x4(b); t3x4(b); t3x4(b);      // T3^16 exact (TST==16)
        cummin_row(jc, b);
        b[0]=fminf(b[0],m0.x); b[1]=fminf(b[1],m0.y); b[2]=fminf(b[2],m0.z); b[3]=fminf(b[3],m0.w);
        b[4]=fminf(b[4],m1.x); b[5]=fminf(b[5],m1.y); b[6]=fminf(b[6],m1.z); b[7]=fminf(b[7],m1.w);
    }
#pragma unroll
    for (int i = 0; i < 8; ++i) prev[i] = b[i];
}

// K1: per-chunk fg/bg flags.
__global__ __launch_bounds__(256) void flags1_kernel(const int* __restrict__ tg,
                                                     int* __restrict__ blkflags) {
    const int4* p = (const int4*)tg + (size_t)blockIdx.x * 4096 + threadIdx.x;
    int fgany = 0, bgany = 0;
#pragma unroll 4
    for (int i = 0; i < 16; ++i) {
        int4 v = p[i * 256];
        fgany |= (v.x | v.y | v.z | v.w);
        bgany |= (v.x == 0) | (v.y == 0) | (v.z == 0) | (v.w == 0);
    }
    int wf = __any(fgany != 0) ? 1 : 0;
    int wb = __any(bgany != 0) ? 2 : 0;
    if ((threadIdx.x & 63) == 0) blkflags[blockIdx.x * 4 + (threadIdx.x >> 6)] = wf | wb;
}

// K2: pass-1 local strip scan (INF incoming) -> Llast + mm1.
__global__ __launch_bounds__(64) void strip1a_kernel(const int* __restrict__ tg,
                                                     const int* __restrict__ blkflags,
                                                     float* __restrict__ Llast,
                                                     float* __restrict__ mm1) {
    const int s = blockIdx.x >> 5, sig = blockIdx.x & 31;
    const int lane = threadIdx.x;
    const int c0 = lane * 8;
    const int* tgb = tg + (size_t)s * NPIX;
    const int fv = sample_flags(blkflags, s, lane);
    const bool useb = (fv & 3) == 3;
    const int R0 = sig * TST;
    float jc[8];
#pragma unroll
    for (int i = 0; i < 8; ++i) jc[i] = A_W * (float)(c0 + i);
    RowBits rA = loadrow_bits(tgb, R0 - 1, c0);
    RowBits rB = loadrow_bits(tgb, R0, c0);
    float prev[8];
#pragma unroll
    for (int i = 0; i < 8; ++i) prev[i] = INF_W;
#pragma unroll 4
    for (int t = 0; t < TST; ++t) {
        RowBits rC = loadrow_bits(tgb, R0 + t + 1, c0);
        int smask = useb ? ((rA.efg | rB.efg | rC.efg) & (rA.ebg | rB.ebg | rC.ebg))
                         : rB.rawbg;
        float dr[8];
#pragma unroll
        for (int i = 0; i < 8; ++i) dr[i] = ((smask >> i) & 1) ? 0.f : INF_W;
        row_step(jc, prev, dr);
        rA = rB; rB = rC;
    }
    float* Lr = Llast + ((size_t)s * NSTRIP + sig) * WDIM + c0;
    *(float4*)Lr       = make_float4(prev[0], prev[1], prev[2], prev[3]);
    *(float4*)(Lr + 4) = make_float4(prev[4], prev[5], prev[6], prev[7]);
    store_minmax(prev, mm1, s * NSTRIP + sig, lane);
}

// K3: pruned bounds1 + exact pass-1 rows -> dB (+LDS) + flipped local scan -> Llast2 + mm2.
__global__ __launch_bounds__(64) void strip3ab_kernel(const int* __restrict__ tg,
                                                      const int* __restrict__ blkflags,
                                                      const float* __restrict__ Llast,
                                                      const float* __restrict__ mm1,
                                                      float* __restrict__ dB,
                                                      float* __restrict__ Llast2,
                                                      float* __restrict__ mm2) {
    const int s = blockIdx.x >> 5, sig = blockIdx.x & 31;
    const int lane = threadIdx.x;
    const int c0 = lane * 8;
    const int* tgb = tg + (size_t)s * NPIX;
    const int fv = sample_flags(blkflags, s, lane);
    const bool useb = (fv & 3) == 3;
    const int R0 = sig * TST;
    float jc[8];
#pragma unroll
    for (int i = 0; i < 8; ++i) jc[i] = A_W * (float)(c0 + i);

    __shared__ float lds[TST][WDIM];   // 32 KB; single-wave block

    float prev[8];
    if (sig == 0) {
#pragma unroll
        for (int i = 0; i < 8; ++i) prev[i] = INF_W;
    } else {
        inline_bounds(Llast + (size_t)s * NSTRIP * WDIM, sig, jc, c0, prev,
                      mm1, s * NSTRIP, lane);
    }

    RowBits rA = loadrow_bits(tgb, R0 - 1, c0);
    RowBits rB = loadrow_bits(tgb, R0, c0);
    float* dst = dB + (size_t)s * NPIX + (size_t)R0 * WDIM;
#pragma unroll 2
    for (int t = 0; t < TST; ++t) {
        RowBits rC = loadrow_bits(tgb, R0 + t + 1, c0);
        int smask = useb ? ((rA.efg | rB.efg | rC.efg) & (rA.ebg | rB.ebg | rC.ebg))
                         : rB.rawbg;
        float dr[8];
#pragma unroll
        for (int i = 0; i < 8; ++i) dr[i] = ((smask >> i) & 1) ? 0.f : INF_W;
        row_step(jc, prev, dr);
        float* p = dst + (size_t)t * WDIM + c0;
        *(float4*)p       = make_float4(prev[0], prev[1], prev[2], prev[3]);
        *(float4*)(p + 4) = make_float4(prev[4], prev[5], prev[6], prev[7]);
        *(float4*)&lds[t][c0]     = make_float4(prev[0], prev[1], prev[2], prev[3]);
        *(float4*)&lds[t][c0 + 4] = make_float4(prev[4], prev[5], prev[6], prev[7]);
        rA = rB; rB = rC;
    }
    __syncthreads();
    // flipped (pass-2) local scan over this strip, INF incoming
#pragma unroll
    for (int i = 0; i < 8; ++i) prev[i] = INF_W;
#pragma unroll 2
    for (int t2 = 0; t2 < TST; ++t2) {
        float4 a = *(const float4*)&lds[TST - 1 - t2][504 - c0];
        float4 q = *(const float4*)&lds[TST - 1 - t2][508 - c0];
        float dr[8];
        dr[7]=a.x; dr[6]=a.y; dr[5]=a.z; dr[4]=a.w;
        dr[3]=q.x; dr[2]=q.y; dr[1]=q.z; dr[0]=q.w;
        row_step(jc, prev, dr);
    }
    const int sig2 = 31 - sig;
    float* Lr = Llast2 + ((size_t)s * NSTRIP + sig2) * WDIM + c0;
    *(float4*)Lr       = make_float4(prev[0], prev[1], prev[2], prev[3]);
    *(float4*)(Lr + 4) = make_float4(prev[4], prev[5], prev[6], prev[7]);
    store_minmax(prev, mm2, s * NSTRIP + sig2, lane);
}

// K4: pruned bounds2 + pass-2 exact rows from dB + fused loss -> sacc.
__global__ __launch_bounds__(64) void strip3bloss_kernel(const float* __restrict__ dB,
                                                         const float* __restrict__ Llast2,
                                                         const float* __restrict__ mm2,
                                                         const float* __restrict__ pred,
                                                         const int* __restrict__ tg,
                                                         float* __restrict__ sacc) {
    const int s = blockIdx.x >> 5, sig2 = blockIdx.x & 31;
    const int lane = threadIdx.x;
    const int c0 = lane * 8;
    const size_t sb = (size_t)s * NPIX;
    float jc[8];
#pragma unroll
    for (int i = 0; i < 8; ++i) jc[i] = A_W * (float)(c0 + i);

    float prev[8];
    if (sig2 == 0) {
#pragma unroll
        for (int i = 0; i < 8; ++i) prev[i] = INF_W;
    } else {
        inline_bounds(Llast2 + (size_t)s * NSTRIP * WDIM, sig2, jc, c0, prev,
                      mm2, s * NSTRIP, lane);
    }

    float mx = 0.f, facc = 0.f, s1 = 0.f, s2 = 0.f, iacc = 0.f, pacc = 0.f;
#pragma unroll 2
    for (int t = 0; t < TST; ++t) {
        int pr = HDIM - 1 - (sig2 * TST + t);
        const size_t rbase = sb + (size_t)pr * WDIM + (WDIM - 8 - c0);
        float4 a = *(const float4*)(dB + rbase);
        float4 b = *(const float4*)(dB + rbase + 4);
        float dr[8];
        dr[7]=a.x; dr[6]=a.y; dr[5]=a.z; dr[4]=a.w;
        dr[3]=b.x; dr[2]=b.y; dr[1]=b.z; dr[0]=b.w;
        float4 xa = *(const float4*)(pred + rbase);
        float4 xb = *(const float4*)(pred + rbase + 4);
        float px[8];
        px[7]=xa.x; px[6]=xa.y; px[5]=xa.z; px[4]=xa.w;
        px[3]=xb.x; px[2]=xb.y; px[1]=xb.z; px[0]=xb.w;
        int4 ta = *(const int4*)(tg + rbase);
        int4 tb = *(const int4*)(tg + rbase + 4);
        int ti[8];
        ti[7]=ta.x; ti[6]=ta.y; ti[5]=ta.z; ti[4]=ta.w;
        ti[3]=tb.x; ti[2]=tb.y; ti[1]=tb.z; ti[0]=tb.w;
        row_step(jc, prev, dr);
#pragma unroll
        for (int i = 0; i < 8; ++i) {
            float x = px[i];
            float dd = prev[i];
            float e = __expf(-fabsf(x));
            float inv = 1.f / (1.f + e);
            float pr_ = (x >= 0.f) ? inv : (1.f - inv);   // sigmoid(x)
            float L = __logf(1.f + e);                    // softplus(-|x|)
            bool t1 = ti[i] != 0;
            float fo = t1 ? 0.25f * (1.f - pr_) * (1.f - pr_) * (fmaxf(-x, 0.f) + L)
                          : 0.75f * pr_ * pr_ * (fmaxf(x, 0.f) + L);
            facc += fo;
            float base = t1 ? (1.f - pr_) : pr_;
            s1 += base;
            s2 += base * dd;
            float tf = t1 ? 1.f : 0.f;
            iacc += tf * pr_;
            pacc += pr_ + tf;
            mx = fmaxf(mx, dd);
        }
    }
#pragma unroll
    for (int off = 32; off > 0; off >>= 1) {
        facc += __shfl_xor(facc, off);
        s1   += __shfl_xor(s1, off);
        s2   += __shfl_xor(s2, off);
        iacc += __shfl_xor(iacc, off);
        pacc += __shfl_xor(pacc, off);
        mx    = fmaxf(mx, __shfl_xor(mx, off));
    }
    if (lane == 0) {
        const int idx = s * NSTRIP + sig2;
        sacc[0 * 512 + idx] = s1;
        sacc[1 * 512 + idx] = s2;
        sacc[2 * 512 + idx] = iacc;
        sacc[3 * 512 + idx] = pacc;
        sacc[4 * 512 + idx] = mx;
        sacc[5 * 512 + idx] = facc;
    }
}

// K5: merged sampred + final.
__global__ __launch_bounds__(64) void final5_kernel(const float* __restrict__ sacc,
                                                    const int* __restrict__ blkflags,
                                                    const float* __restrict__ lv,
                                                    float* __restrict__ out) {
    const int lane = threadIdx.x;
    const int j = lane & 31;
    float fsum = 0.f, bsum = 0.f, dsum = 0.f, isum = 0.f;
    for (int k = 0; k < 8; ++k) {
        int ss = 2 * k + (lane >> 5);
        int idx = ss * NSTRIP + j;
        float t1 = sacc[0 * 512 + idx];
        float t2 = sacc[1 * 512 + idx];
        float ia = sacc[2 * 512 + idx];
        float pa = sacc[3 * 512 + idx];
        float mx = sacc[4 * 512 + idx];
        float fa = sacc[5 * 512 + idx];
        int   vv = blkflags[ss * 64 + j] | blkflags[ss * 64 + 32 + j];
#pragma unroll
        for (int off = 16; off > 0; off >>= 1) {
            t1 += __shfl_xor(t1, off);
            t2 += __shfl_xor(t2, off);
            ia += __shfl_xor(ia, off);
            pa += __shfl_xor(pa, off);
            fa += __shfl_xor(fa, off);
            mx  = fmaxf(mx, __shfl_xor(mx, off));
            vv |= __shfl_xor(vv, off);
        }
        bool hfg = (vv & 1) != 0;
        if (j == 0) {
            fsum += fa;
            float distsum = hfg ? ((mx > 0.f) ? t2 / fmaxf(mx, 1e-12f) : 0.f) : t1;
            bsum += t1 + distsum;
            dsum += (2.f * ia + 1e-6f) / (pa + 1e-6f);
            isum += (ia + 1e-6f) / (pa - ia + 1e-6f);
        }
    }
    fsum += __shfl_xor(fsum, 32);
    bsum += __shfl_xor(bsum, 32);
    dsum += __shfl_xor(dsum, 32);
    isum += __shfl_xor(isum, 32);
    if (lane == 0) {
        float focal = fsum / NTOT_F;
        float bnd   = bsum / NTOT_F;
        float dice = 1.f - dsum / 16.f;
        float iou  = 1.f - isum / 16.f;
        float l0 = lv[0], l1 = lv[1], l2 = lv[2], l3 = lv[3];
        float total = expf(-l0) * focal + l0 + expf(-l1) * dice + l1
                    + expf(-l2) * bnd  + l2 + expf(-l3) * iou  + l3;
        out[0] = total; out[1] = focal; out[2] = dice; out[3] = bnd; out[4] = iou;
    }
}

extern "C" void kernel_launch(void* const* d_in, const int* in_sizes, int n_in,
                              void* d_out, int out_size, void* d_ws, size_t ws_size,
                              hipStream_t stream) {
    const float* pred = (const float*)d_in[0];
    const int*   tg   = (const int*)d_in[1];
    const float* lv   = (const float*)d_in[2];
    float* out = (float*)d_out;
    char* ws = (char*)d_ws;
    int*   blkflags = (int*)(ws + 1024);
    float* sacc     = (float*)(ws + OFF_SACC);
    float* mm1      = (float*)(ws + OFF_MM1);
    float* mm2      = (float*)(ws + OFF_MM2);
    float* Llast    = (float*)(ws + OFF_LLAST);
    float* Llast2   = (float*)(ws + OFF_LLAST2);
    float* dB       = (float*)(ws + OFF_DB);

    flags1_kernel<<<256, 256, 0, stream>>>(tg, blkflags);
    strip1a_kernel<<<NSAMP * NSTRIP, 64, 0, stream>>>(tg, blkflags, Llast, mm1);
    strip3ab_kernel<<<NSAMP * NSTRIP, 64, 0, stream>>>(tg, blkflags, Llast, mm1, dB, Llast2, mm2);
    strip3bloss_kernel<<<NSAMP * NSTRIP, 64, 0, stream>>>(dB, Llast2, mm2, pred, tg, sacc);
    final5_kernel<<<1, 64, 0, stream>>>(sacc, blkflags, lv, out);
}